// Round 1
// baseline (4006.173 us; speedup 1.0000x reference)
//
#include <hip/hip_runtime.h>
#include <hip/hip_bf16.h>

#define Bc 8
#define Tc 100
#define Ac 64
#define Hc 512
#define Lc 3
#define BAc 512   // Bc*Ac
#define H3c 1536

typedef short bf16x8 __attribute__((ext_vector_type(8)));
typedef float f32x4 __attribute__((ext_vector_type(4)));

__device__ __forceinline__ unsigned short f2bf(float f) {
  unsigned int u = __float_as_uint(f);
  u += 0x7FFFu + ((u >> 16) & 1u);   // round-to-nearest-even
  return (unsigned short)(u >> 16);
}

__global__ __launch_bounds__(256) void conv_bf16(const float* __restrict__ src,
                                                 unsigned short* __restrict__ dst,
                                                 int n4) {
  int i = blockIdx.x * 256 + threadIdx.x;
  if (i >= n4) return;
  f32x4 v = *(const f32x4*)(src + (size_t)i * 4);
  ushort4 o;
  o.x = f2bf(v[0]); o.y = f2bf(v[1]); o.z = f2bf(v[2]); o.w = f2bf(v[3]);
  *(ushort4*)(dst + (size_t)i * 4) = o;
}

// One diagonal s = t + l. Grid = 3*256 blocks of 64 threads; block (l, r8) computes
// the 32x32 h-tile of layer l at t = s - l. Each block does 6 GEMM tiles
// (ir,iz,in,hr,hz,hn) of [32 rows x 32 cols], K=512, via 16x16x32 bf16 MFMA with
// direct-from-global fragment loads, then the fused GRU gate epilogue.
__global__ __launch_bounds__(64) void gru_wave(
    const float* __restrict__ x,     // [B,T,A,H] f32
    const short* __restrict__ wbih,  // [L,3H,H] bf16
    const short* __restrict__ wbhh,  // [L,3H,H] bf16
    const float* __restrict__ bih,   // [L,3H] f32
    const float* __restrict__ bhh,   // [L,3H] f32
    short* hb,                       // [2,L,BA,H] bf16 (parity double buffer)
    float* hf,                       // [L,BA,H] f32
    const int* __restrict__ valid,   // [B,T,A] int32 (0/1)
    float* __restrict__ y,           // [B,T,A,H] f32 output
    int s) {
  int bid = blockIdx.x;
  int l = bid >> 8;
  int t = s - l;
  if (t < 0 || t >= Tc) return;
  int r8 = bid & 255;
  // XCD-aware: XCD = bid%8; give each XCD a consecutive pair of column blocks
  // so its weight working set (~1.2 MB over 3 layers) stays L2-resident.
  int cb = ((r8 & 7) << 1) | ((r8 >> 3) & 1);
  int rm = r8 >> 4;
  int m0 = rm * 32, c0 = cb * 32;
  int lane = threadIdx.x;
  int lrow = lane & 15;
  int kgrp = lane >> 4;
  int kofs = kgrp * 8;
  int par = t & 1;

  const short* Wih = wbih + (size_t)l * H3c * Hc;
  const short* Whh = wbhh + (size_t)l * H3c * Hc;
  const float* bihl = bih + l * H3c;
  const float* bhhl = bhh + l * H3c;
  const short* Ah = hb + ((size_t)(1 - par) * Lc + l) * BAc * Hc;  // h_l at t-1
  float* hst = hf + (size_t)l * BAc * Hc;                          // f32 h_l (t-1 -> t)
  short* hbo = hb + ((size_t)par * Lc + l) * BAc * Hc;             // bf16 h_l at t

  f32x4 acc[6][2][2];
#pragma unroll
  for (int o = 0; o < 6; ++o)
#pragma unroll
    for (int fi = 0; fi < 2; ++fi)
#pragma unroll
      for (int fj = 0; fj < 2; ++fj)
        acc[o][fi][fj] = f32x4{0.f, 0.f, 0.f, 0.f};

  // B-operand pointers: lane reads w[n = gate*512 + c][k..k+7] (row-major, K contiguous)
  const short* pBi[3][2];
  const short* pBh[3][2];
#pragma unroll
  for (int g = 0; g < 3; ++g)
#pragma unroll
    for (int fj = 0; fj < 2; ++fj) {
      int n = g * Hc + c0 + fj * 16 + lrow;
      pBi[g][fj] = Wih + (size_t)n * Hc + kofs;
      pBh[g][fj] = Whh + (size_t)n * Hc + kofs;
    }
  const short* pAh0 = Ah + (size_t)(m0 + lrow) * Hc + kofs;
  const short* pAh1 = pAh0 + 16 * Hc;

#define MFMA_BLOCK(ko)                                                                   \
  _Pragma("unroll") for (int g = 0; g < 3; ++g) {                                        \
    _Pragma("unroll") for (int fj = 0; fj < 2; ++fj) {                                   \
      bf16x8 bi = *(const bf16x8*)(pBi[g][fj] + (ko));                                   \
      bf16x8 bh = *(const bf16x8*)(pBh[g][fj] + (ko));                                   \
      acc[g][0][fj] = __builtin_amdgcn_mfma_f32_16x16x32_bf16(ai0, bi, acc[g][0][fj], 0, 0, 0);   \
      acc[g][1][fj] = __builtin_amdgcn_mfma_f32_16x16x32_bf16(ai1, bi, acc[g][1][fj], 0, 0, 0);   \
      acc[3 + g][0][fj] = __builtin_amdgcn_mfma_f32_16x16x32_bf16(ah0, bh, acc[3 + g][0][fj], 0, 0, 0); \
      acc[3 + g][1][fj] = __builtin_amdgcn_mfma_f32_16x16x32_bf16(ah1, bh, acc[3 + g][1][fj], 0, 0, 0); \
    }                                                                                    \
  }

  if (l == 0) {
    // layer-0 input: x[t], fp32 strided layout [B,T,A,H]; convert to bf16 on the fly
    int mA = m0 + lrow, mB = mA + 16;
    const float* pX0 = x + (((size_t)(mA >> 6) * Tc + t) * Ac + (mA & 63)) * Hc + kofs;
    const float* pX1 = x + (((size_t)(mB >> 6) * Tc + t) * Ac + (mB & 63)) * Hc + kofs;
#pragma unroll 2
    for (int kk = 0; kk < 16; ++kk) {
      int ko = kk * 32;
      f32x4 xa0 = *(const f32x4*)(pX0 + ko);
      f32x4 xa1 = *(const f32x4*)(pX0 + ko + 4);
      f32x4 xb0 = *(const f32x4*)(pX1 + ko);
      f32x4 xb1 = *(const f32x4*)(pX1 + ko + 4);
      bf16x8 ai0, ai1;
#pragma unroll
      for (int e = 0; e < 4; ++e) {
        ai0[e]     = (short)f2bf(xa0[e]);
        ai0[4 + e] = (short)f2bf(xa1[e]);
        ai1[e]     = (short)f2bf(xb0[e]);
        ai1[4 + e] = (short)f2bf(xb1[e]);
      }
      bf16x8 ah0 = *(const bf16x8*)(pAh0 + ko);
      bf16x8 ah1 = *(const bf16x8*)(pAh1 + ko);
      MFMA_BLOCK(ko)
    }
  } else {
    // layer l>0 input: h_{l-1} at t (written by previous diagonal), bf16 buffer
    const short* Ain = hb + ((size_t)par * Lc + (l - 1)) * BAc * Hc;
    const short* pA0 = Ain + (size_t)(m0 + lrow) * Hc + kofs;
    const short* pA1 = pA0 + 16 * Hc;
#pragma unroll 2
    for (int kk = 0; kk < 16; ++kk) {
      int ko = kk * 32;
      bf16x8 ai0 = *(const bf16x8*)(pA0 + ko);
      bf16x8 ai1 = *(const bf16x8*)(pA1 + ko);
      bf16x8 ah0 = *(const bf16x8*)(pAh0 + ko);
      bf16x8 ah1 = *(const bf16x8*)(pAh1 + ko);
      MFMA_BLOCK(ko)
    }
  }

  // Epilogue: C/D frag mapping (m89-verified): col = lane&15, row = (lane>>4)*4 + reg
#pragma unroll
  for (int fi = 0; fi < 2; ++fi) {
#pragma unroll
    for (int r = 0; r < 4; ++r) {
      int m = m0 + fi * 16 + kgrp * 4 + r;
      int bb = m >> 6, aa = m & 63;
      int vld = valid[((size_t)bb * Tc + t) * Ac + aa];
#pragma unroll
      for (int fj = 0; fj < 2; ++fj) {
        int c = c0 + fj * 16 + lrow;
        float ir = acc[0][fi][fj][r] + bihl[c];
        float iz = acc[1][fi][fj][r] + bihl[Hc + c];
        float inn = acc[2][fi][fj][r] + bihl[2 * Hc + c];
        float hr = acc[3][fi][fj][r] + bhhl[c];
        float hz = acc[4][fi][fj][r] + bhhl[Hc + c];
        float hn = acc[5][fi][fj][r] + bhhl[2 * Hc + c];
        float rg = 1.0f / (1.0f + __expf(-(ir + hr)));
        float zg = 1.0f / (1.0f + __expf(-(iz + hz)));
        float ng = tanhf(inn + rg * hn);
        size_t hidx = (size_t)m * Hc + c;
        float hp = hst[hidx];
        float hnew = (1.0f - zg) * ng + zg * hp;
        if (!vld) hnew = 0.0f;
        hst[hidx] = hnew;
        hbo[hidx] = (short)f2bf(hnew);
        if (l == 2) y[(((size_t)bb * Tc + t) * Ac + aa) * Hc + c] = hnew;
      }
    }
  }
#undef MFMA_BLOCK
}

extern "C" void kernel_launch(void* const* d_in, const int* in_sizes, int n_in,
                              void* d_out, int out_size, void* d_ws, size_t ws_size,
                              hipStream_t stream) {
  const float* x = (const float*)d_in[0];
  const int* valid = (const int*)d_in[1];
  const float* w_ih = (const float*)d_in[2];
  const float* w_hh = (const float*)d_in[3];
  const float* b_ih = (const float*)d_in[4];
  const float* b_hh = (const float*)d_in[5];
  float* y = (float*)d_out;

  // workspace layout (≈15.7 MB total)
  char* ws = (char*)d_ws;
  const size_t welems = (size_t)Lc * H3c * Hc;           // 2,359,296
  unsigned short* wbih = (unsigned short*)ws;            // welems bf16
  unsigned short* wbhh = (unsigned short*)(ws + welems * 2);
  short* hb = (short*)(ws + welems * 4);                 // [2,L,BA,H] bf16
  float* hf = (float*)(ws + welems * 4 + (size_t)2 * Lc * BAc * Hc * 2);

  int n4 = (int)(welems / 4);
  conv_bf16<<<(n4 + 255) / 256, 256, 0, stream>>>(w_ih, wbih, n4);
  conv_bf16<<<(n4 + 255) / 256, 256, 0, stream>>>(w_hh, wbhh, n4);
  (void)hipMemsetAsync(hb, 0, (size_t)2 * Lc * BAc * Hc * 2, stream);
  (void)hipMemsetAsync(hf, 0, (size_t)Lc * BAc * Hc * 4, stream);

  // diagonal wavefront: stage s runs cells (t = s - l, l) for l = 0..2
  for (int s = 0; s < Tc + Lc - 1; ++s) {
    gru_wave<<<Lc * 256, 64, 0, stream>>>(x, (const short*)wbih, (const short*)wbhh,
                                          b_ih, b_hh, hb, hf, valid, y, s);
  }
}